// Round 5
// baseline (439.186 us; speedup 1.0000x reference)
//
#include <hip/hip_runtime.h>
#include <hip/hip_bf16.h>

// LatentSDE: y' = f_post(t,y) dt + sigma dW, f_post = MLP(2->512->512->1, tanh).
// Phase 1: tabulate f per (step, y-grid) via fused MFMA GEMM (68k rows x 512 x 512).
// Phase 1c: Catmull-Rom cubic coeffs per (step, cell).
// Phase 2: serial scan, one thread per batch elem.
// Round-5 fix: rounds 1-4 all landed ~145-175us because the AMDGPU scheduler
//   minimizes VGPR pressure toward a default occupancy target (r4: VGPR=96 vs
//   ~190 needed) — it SANK the ring refill loads to their uses / spilled ring
//   slots, putting full L2/HBM latency back on the serial chain. Fix:
//   amdgpu_waves_per_eu(1,1) (occupancy is batch-limited to 2 waves/CU anyway)
//   gives the allocator the true 512-VGPR budget; sched_barrier(0) fences pin
//   the gather-issue / refill groups in program order.
// Structure (from r4): per 8-step block, gather cell indices are PREDICTED from
//   block-start v + Brownian prefix (drift <= ~0.2 cells over 8 steps; Catmull-
//   Rom is C^1 so neighbor-cell evaluation slightly outside [0,1) is 2nd-order
//   accurate). All 32 ds_bpermutes issue up front; exact chain runs at VALU
//   dependency speed. Rings: cr[24] float4 rows (lane l = cell l), dwr[24].

typedef __bf16 bf16x8 __attribute__((ext_vector_type(8)));
typedef float floatx4 __attribute__((ext_vector_type(4)));

#define NUM_STEPS 1000
#define BATCH 32768
#define HID 512
#define G_PTS 68             // stored y-grid points per step (64 cells + CR halo)
#define G_CELLS 64
#define P1_BLOCKS 1063       // * 64 rows = 68032 >= 1000*68
#define DT_F 0.001f
#define Y_LO (-4.0f)
#define DY 0.125f
#define INV_DY 8.0f

// force global (addrspace 1) memory ops — guarantees global_*, never flat_*
template <typename T>
__device__ __forceinline__ T gload(const T* p){
  return *(const T __attribute__((address_space(1)))*)((unsigned long long)p);
}
template <typename T>
__device__ __forceinline__ void gstore(T* p, T v){
  *(T __attribute__((address_space(1)))*)((unsigned long long)p) = v;
}

// tanh(x) = 1 - 2/(exp(2x)+1); saturates correctly for |x| large
__device__ __forceinline__ float tanh_fast(float x){
  float e = __expf(2.0f * x);
  return 1.0f - 2.0f / (e + 1.0f);
}

// ---------------- P0: W2 f32 [k][j] -> W2T bf16 [j][k] (512x512) ---------------
__global__ __launch_bounds__(256) void p0_transpose(const float* __restrict__ W2,
                                                    __bf16* __restrict__ W2T){
  int tid = blockIdx.x * 256 + threadIdx.x;
  #pragma unroll
  for (int r = 0; r < 4; ++r){
    int idx = tid + r * 65536;
    int a = idx >> 9, b = idx & 511;
    W2T[a * 512 + b] = (__bf16)W2[b * 512 + a];   // W2T[j][k] = W2[k][j]
  }
}

// ---------------- P1: h1 -> GEMM(W2) -> tanh -> dot(W3) => V[n*68+g] -----------
// Block: 256 thr = 4 waves, tile BM=64 rows x BN=512 (all cols), K-loop 32.
// MFMA 16x16x32 bf16. A: A[m=lane&15][k=quad*8+j]; B: B[k=quad*8+j][n=lane&15];
// C/D: col=lane&15, row=quad*4+reg (m89-verified).
__global__ __launch_bounds__(256, 2) void p1_gemm(
    const float* __restrict__ W1,
    const float* __restrict__ b1,
    const __bf16* __restrict__ W2T,
    const float* __restrict__ b2,
    const float* __restrict__ W3,
    const float* __restrict__ b3,
    float* __restrict__ V)
{
  __shared__ __align__(16) __bf16 Alds[64 * 40];    // 64 rows x 32 k, pad->40
  __shared__ __align__(16) __bf16 Blds[512 * 40];   // 512 cols x 32 k, pad->40
  __shared__ float red[4][64];

  const int tid  = threadIdx.x;
  const int bm   = blockIdx.x * 64;
  const int wave = tid >> 6;
  const int lane = tid & 63;
  const int quad = lane >> 4;
  const int l15  = lane & 15;

  // A-staging: 4 threads per row, each computes 8 h1 values per K-iter
  const int arow = tid >> 2;
  const int jb   = (tid & 3) * 8;
  const int r    = bm + arow;
  const int n    = r / G_PTS;
  const int g    = r - n * G_PTS;
  const float t  = (float)n * DT_F;
  const float yg = Y_LO + (float)(g - 1) * DY;   // halo point at g=0

  floatx4 acc[4][8];
  #pragma unroll
  for (int mt = 0; mt < 4; ++mt)
    #pragma unroll
    for (int nt = 0; nt < 8; ++nt){
      floatx4 z = {0.f, 0.f, 0.f, 0.f};
      acc[mt][nt] = z;
    }

  for (int kk = 0; kk < HID; kk += 32){
    // stage A: h1_j = tanh(t*W1[0,j] + y*W1[1,j] + b1[j]) for j = kk+jb..+7
    {
      const float* wt = W1 + kk + jb;          // row 0 of W1 (t weight)
      const float* wy = W1 + 512 + kk + jb;    // row 1 of W1 (y weight)
      const float* bp = b1 + kk + jb;
      bf16x8 hv;
      #pragma unroll
      for (int e = 0; e < 8; ++e){
        float z = fmaf(t, wt[e], fmaf(yg, wy[e], bp[e]));
        hv[e] = (__bf16)tanh_fast(z);
      }
      *reinterpret_cast<bf16x8*>(&Alds[arow * 40 + jb]) = hv;
    }
    // stage B: Blds[col][k] = W2T[col][kk+k]
    #pragma unroll
    for (int c8 = 0; c8 < 8; ++c8){
      int c = tid + c8 * 256;                  // 0..2047
      int nn = c >> 2, part = c & 3;
      bf16x8 v = *reinterpret_cast<const bf16x8*>(&W2T[nn * 512 + kk + part * 8]);
      *reinterpret_cast<bf16x8*>(&Blds[nn * 40 + part * 8]) = v;
    }
    __syncthreads();

    bf16x8 aF[4];
    #pragma unroll
    for (int mt = 0; mt < 4; ++mt)
      aF[mt] = *reinterpret_cast<const bf16x8*>(&Alds[(mt * 16 + l15) * 40 + quad * 8]);
    #pragma unroll
    for (int nt = 0; nt < 8; ++nt){
      bf16x8 bF = *reinterpret_cast<const bf16x8*>(&Blds[(wave * 128 + nt * 16 + l15) * 40 + quad * 8]);
      #pragma unroll
      for (int mt = 0; mt < 4; ++mt)
        acc[mt][nt] = __builtin_amdgcn_mfma_f32_16x16x32_bf16(aF[mt], bF, acc[mt][nt], 0, 0, 0);
    }
    __syncthreads();
  }

  // epilogue: V[row] = b3 + sum_k W3[k] * tanh(z[row][k] + b2[k])
  float p[4][4];
  #pragma unroll
  for (int mt = 0; mt < 4; ++mt)
    #pragma unroll
    for (int rg = 0; rg < 4; ++rg) p[mt][rg] = 0.f;

  #pragma unroll
  for (int nt = 0; nt < 8; ++nt){
    int col = wave * 128 + nt * 16 + l15;
    float b2v = b2[col];
    float w3v = W3[col];
    #pragma unroll
    for (int mt = 0; mt < 4; ++mt)
      #pragma unroll
      for (int rg = 0; rg < 4; ++rg)
        p[mt][rg] += tanh_fast(acc[mt][nt][rg] + b2v) * w3v;
  }
  #pragma unroll
  for (int off = 1; off < 16; off <<= 1)
    #pragma unroll
    for (int mt = 0; mt < 4; ++mt)
      #pragma unroll
      for (int rg = 0; rg < 4; ++rg)
        p[mt][rg] += __shfl_xor(p[mt][rg], off, 64);

  if (l15 == 0){
    #pragma unroll
    for (int mt = 0; mt < 4; ++mt)
      #pragma unroll
      for (int rg = 0; rg < 4; ++rg)
        red[wave][mt * 16 + quad * 4 + rg] = p[mt][rg];
  }
  __syncthreads();
  if (tid < 64){
    float s = red[0][tid] + red[1][tid] + red[2][tid] + red[3][tid] + b3[0];
    V[bm + tid] = s;
  }
}

// ---------------- P1c: Catmull-Rom coeffs per (step, cell) ---------------------
__global__ __launch_bounds__(256) void p1_coeff(const float* __restrict__ V,
                                                float4* __restrict__ C,
                                                float* __restrict__ sum_out){
  if (blockIdx.x == 0 && threadIdx.x == 0) sum_out[0] = 0.f;
  int cell = blockIdx.x * 256 + threadIdx.x;   // 64000 total
  int nn = cell >> 6;
  int j  = cell & 63;
  const float* v = &V[nn * G_PTS + j];
  float pm1 = v[0], p0 = v[1], p1 = v[2], p2 = v[3];
  float4 c;
  c.x = p0;
  c.y = 0.5f * (p1 - pm1);
  c.z = pm1 - 2.5f * p0 + 2.0f * p1 - 0.5f * p2;
  c.w = 1.5f * (p0 - p1) + 0.5f * (p2 - pm1);
  C[cell] = c;
}

// ---------------- P2: the serial scan, one thread per batch element ------------
// State v = 8y+32. Per 8-step block: (1) Brownian-prefix index prediction (k=0
// exact); (2) issue all 32 ds_bpermutes; (3) refill freed ring slots (rows +24);
// (4) exact chain: med3 -> s=u-jf -> split Horner -> v, at VALU latency.
// amdgpu_waves_per_eu(1,1): true 512-VGPR budget so the rings stay register-
// resident (r4's VGPR=96 proved the scheduler was sinking/spilling them).
__global__ __attribute__((amdgpu_waves_per_eu(1, 1)))
__launch_bounds__(128, 1) void p2_scan(
    const float* __restrict__ eps,
    const float* __restrict__ dW,
    const float* __restrict__ qm,
    const float* __restrict__ qlv,
    const float4* __restrict__ Cin,
    float* __restrict__ out,
    float* __restrict__ sum_out)
{
  __shared__ float wsum[2];
  const int tid  = threadIdx.x;
  const int w    = tid >> 6;
  const int lane = tid & 63;
  const int i    = blockIdx.x * 128 + tid;
  const floatx4* C = reinterpret_cast<const floatx4*>(Cin);

  float qmean = qm[0];
  float qstd  = __expf(0.5f * qlv[0]);
  float yv0 = fmaf(gload(eps + i), qstd, qmean);
  float vst = fmaf(yv0, 8.0f, 32.0f);      // u-space state
  float acc2 = 0.f;
  float* orow = out + (size_t)i * NUM_STEPS;

  // rings: 24 rows (3 blocks). Slot r%24 holds row r. Lane l = cell l's coeffs.
  floatx4 cr[24];
  float   dwr[24];
  #pragma unroll
  for (int k = 0; k < 24; ++k){
    cr[k]  = gload(C + k * G_CELLS + lane);
    dwr[k] = gload(dW + k * BATCH + i);
  }

  floatx4 ybuf = {0.f, 0.f, 0.f, 0.f};

#define GBLOCK(PH, B)                                                          \
  {                                                                            \
    float jf[8]; int j4[8]; float fdw[8];                                      \
    int icx[8], icy[8], icz[8], icw[8];                                        \
    /* 1) index prediction: v_hat_k = v_B + 4*sum_{m<k} dw_m (k=0 exact) */    \
    float pv = vst;                                                            \
    _Pragma("unroll")                                                          \
    for (int k = 0; k < 8; ++k){                                               \
      fdw[k] = dwr[(PH)*8 + k] * 4.0f;                                         \
      float up = __builtin_amdgcn_fmed3f(pv, 0.0f, 63.999f);                   \
      int jp = (int)up;                                                        \
      jf[k] = (float)jp;                                                       \
      j4[k] = jp << 2;                                                         \
      pv += fdw[k];                                                            \
    }                                                                          \
    /* 2) issue all gathers, step order (counted lgkm waits line up) */        \
    _Pragma("unroll")                                                          \
    for (int k = 0; k < 8; ++k){                                               \
      icx[k] = __builtin_amdgcn_ds_bpermute(j4[k], __float_as_int(cr[(PH)*8+k][0])); \
      icy[k] = __builtin_amdgcn_ds_bpermute(j4[k], __float_as_int(cr[(PH)*8+k][1])); \
      icz[k] = __builtin_amdgcn_ds_bpermute(j4[k], __float_as_int(cr[(PH)*8+k][2])); \
      icw[k] = __builtin_amdgcn_ds_bpermute(j4[k], __float_as_int(cr[(PH)*8+k][3])); \
    }                                                                          \
    __builtin_amdgcn_sched_barrier(0);                                         \
    /* 3) refill freed slots with rows B+24..B+31 (used 3 blocks later) */     \
    _Pragma("unroll")                                                          \
    for (int k = 0; k < 8; ++k){                                               \
      int rr = (B) + 24 + k; rr = rr > 999 ? 999 : rr;                         \
      cr[(PH)*8 + k]  = gload(C + rr * G_CELLS + lane);                        \
      dwr[(PH)*8 + k] = gload(dW + rr * BATCH + i);                            \
    }                                                                          \
    __builtin_amdgcn_sched_barrier(0);                                         \
    /* 4) exact chain at VALU speed */                                         \
    _Pragma("unroll")                                                          \
    for (int k = 0; k < 8; ++k){                                               \
      float u  = __builtin_amdgcn_fmed3f(vst, 0.0f, 63.999f);                  \
      float t1 = vst + fdw[k];                                                 \
      float q  = fmaf(vst, 0.25f, -10.0f);     /* 2y-2 in u-space */           \
      float s  = u - jf[k];                    /* may be slightly outside [0,1) */ \
      float tlo = fmaf(s, __int_as_float(icy[k]), __int_as_float(icx[k]));     \
      float thi = fmaf(s, __int_as_float(icw[k]), __int_as_float(icz[k]));     \
      float s2  = s * s;                                                       \
      float f   = fmaf(s2, thi, tlo);                                          \
      float uu  = fmaf(2.0f, f, q);                                            \
      acc2 = fmaf(uu, uu, acc2);                                               \
      vst = fmaf(f, 8.0f * DT_F, t1);                                          \
      float yo = fmaf(vst, 0.125f, -4.0f);                                     \
      if      ((k & 3) == 0) ybuf[0] = yo;                                     \
      else if ((k & 3) == 1) ybuf[1] = yo;                                     \
      else if ((k & 3) == 2) ybuf[2] = yo;                                     \
      else { ybuf[3] = yo;                                                     \
             gstore(reinterpret_cast<floatx4*>(orow + (B) + k - 3), ybuf); }   \
    }                                                                          \
  }

  for (int bb = 0; bb < 984; bb += 24){
    GBLOCK(0, bb);
    GBLOCK(1, bb + 8);
    GBLOCK(2, bb + 16);
  }
  GBLOCK(0, 984);
  GBLOCK(1, 992);
#undef GBLOCK

  float lq = 0.5f * DT_F * acc2;
  #pragma unroll
  for (int off = 1; off < 64; off <<= 1)
    lq += __shfl_xor(lq, off, 64);
  if (lane == 0) wsum[w] = lq;
  __syncthreads();
  if (tid == 0) atomicAdd(sum_out, wsum[0] + wsum[1]);
}

// ---------------- P3: kl0 + mean(logqp) -> out[last] ---------------------------
__global__ void p3_final(const float* __restrict__ qm,
                         const float* __restrict__ qlv,
                         const float* __restrict__ sum_in,
                         float* __restrict__ out){
  float qmean = qm[0];
  float qstd  = __expf(0.5f * qlv[0]);
  const float pstd = 0.35355339059327373f;        // sigma/sqrt(2*theta)
  float ratio = qstd / pstd;
  float dm = 1.0f - qmean;                        // MU - qy0_mean
  float kl0 = 0.5f * (ratio * ratio + (dm * dm) / (pstd * pstd)
                      - 1.0f + __logf(pstd / qstd));
  out[(size_t)BATCH * NUM_STEPS] = kl0 + sum_in[0] * (1.0f / 32768.0f);
}

extern "C" void kernel_launch(void* const* d_in, const int* in_sizes, int n_in,
                              void* d_out, int out_size, void* d_ws, size_t ws_size,
                              hipStream_t stream){
  const float* W1  = (const float*)d_in[0];
  const float* b1  = (const float*)d_in[1];
  const float* W2  = (const float*)d_in[2];
  const float* b2  = (const float*)d_in[3];
  const float* W3  = (const float*)d_in[4];
  const float* b3  = (const float*)d_in[5];
  const float* qm  = (const float*)d_in[6];
  const float* qlv = (const float*)d_in[7];
  const float* eps = (const float*)d_in[8];
  const float* dW  = (const float*)d_in[9];
  float* out = (float*)d_out;

  // workspace: W2T 512KB | V 272KB | C 1MB | sum
  char* ws = (char*)d_ws;
  __bf16* W2T = (__bf16*)(ws);
  float*  V   = (float*)(ws + 524288);
  float4* C   = (float4*)(ws + 796416);
  float*  sum = (float*)(ws + 1820416);

  p0_transpose<<<256, 256, 0, stream>>>(W2, W2T);
  p1_gemm<<<P1_BLOCKS, 256, 0, stream>>>(W1, b1, W2T, b2, W3, b3, V);
  p1_coeff<<<250, 256, 0, stream>>>(V, C, sum);
  p2_scan<<<BATCH / 128, 128, 0, stream>>>(eps, dW, qm, qlv, C, out, sum);
  p3_final<<<1, 1, 0, stream>>>(qm, qlv, sum, out);
}

// Round 6
// 427.328 us; speedup vs baseline: 1.0277x; 1.0277x over previous
//
#include <hip/hip_runtime.h>
#include <hip/hip_bf16.h>

// LatentSDE: y' = f_post(t,y) dt + sigma dW, f_post = MLP(2->512->512->1, tanh).
// Phase 1: tabulate f per (step, y-grid) via fused MFMA GEMM (68k rows x 512 x 512).
// Phase 1c: Catmull-Rom cubic coeffs per (step, cell).
// Phase 2: serial scan, one thread per batch elem. Round-6 rework:
//   r1-r5 all hit ~150us because the LLVM AMDGPU scheduler refuses to keep
//   large prefetch RINGS register-resident (r4 VGPR=96, r5 VGPR=132 vs ~190
//   needed) — refill loads get sunk to uses / slots spilled, putting HBM
//   latency back on the serial chain. Fix: the prefetch buffer moves to LDS,
//   filled by global_load_lds DMA (hardware-addressed, nothing to sink/spill).
//   - 1 wave/block (64 thr, 512 blocks), wave-private LDS, zero barriers.
//   - Double-buffered 16-step chunks: cl[2][16][64] f4 (32KB) + dwl[2][16][64]
//     (8KB) = 40KB -> 4 blocks/CU capacity (2 needed).
//   - Chunk c+2 issued AFTER chunk c is consumed; boundary = counted
//     "s_waitcnt vmcnt(4)" (4 trailing stores) + sched_barrier(0). DMA flight
//     time = one full chunk (~1000cy) >= HBM latency, off-chain.
//   - Per 8-step block (r4 structure, accuracy validated): 8 ds_read_b32 dW,
//     Brownian-prefix index prediction, 8 predicted ds_read_b128 gathers,
//     exact chain at VALU dependency speed.

typedef __bf16 bf16x8 __attribute__((ext_vector_type(8)));
typedef float floatx4 __attribute__((ext_vector_type(4)));
typedef unsigned int u32;
typedef const __attribute__((address_space(1))) u32* gp32;
typedef __attribute__((address_space(3))) u32* lp32;

#define NUM_STEPS 1000
#define BATCH 32768
#define HID 512
#define G_PTS 68             // stored y-grid points per step (64 cells + CR halo)
#define G_CELLS 64
#define P1_BLOCKS 1063       // * 64 rows = 68032 >= 1000*68
#define DT_F 0.001f
#define Y_LO (-4.0f)
#define DY 0.125f
#define INV_DY 8.0f

// force global (addrspace 1) memory ops — guarantees global_*, never flat_*
template <typename T>
__device__ __forceinline__ T gload(const T* p){
  return *(const T __attribute__((address_space(1)))*)((unsigned long long)p);
}
template <typename T>
__device__ __forceinline__ void gstore(T* p, T v){
  *(T __attribute__((address_space(1)))*)((unsigned long long)p) = v;
}

// global->LDS DMA. LDS dest is wave-uniform base + lane*size; global src per-lane.
__device__ __forceinline__ void dma16(const void* g, void* l){
  __builtin_amdgcn_global_load_lds((gp32)g, (lp32)l, 16, 0, 0);
}
__device__ __forceinline__ void dma4(const void* g, void* l){
  __builtin_amdgcn_global_load_lds((gp32)g, (lp32)l, 4, 0, 0);
}

// tanh(x) = 1 - 2/(exp(2x)+1); saturates correctly for |x| large
__device__ __forceinline__ float tanh_fast(float x){
  float e = __expf(2.0f * x);
  return 1.0f - 2.0f / (e + 1.0f);
}

// ---------------- P0: W2 f32 [k][j] -> W2T bf16 [j][k] (512x512) ---------------
__global__ __launch_bounds__(256) void p0_transpose(const float* __restrict__ W2,
                                                    __bf16* __restrict__ W2T){
  int tid = blockIdx.x * 256 + threadIdx.x;
  #pragma unroll
  for (int r = 0; r < 4; ++r){
    int idx = tid + r * 65536;
    int a = idx >> 9, b = idx & 511;
    W2T[a * 512 + b] = (__bf16)W2[b * 512 + a];   // W2T[j][k] = W2[k][j]
  }
}

// ---------------- P1: h1 -> GEMM(W2) -> tanh -> dot(W3) => V[n*68+g] -----------
// Block: 256 thr = 4 waves, tile BM=64 rows x BN=512 (all cols), K-loop 32.
// MFMA 16x16x32 bf16. A: A[m=lane&15][k=quad*8+j]; B: B[k=quad*8+j][n=lane&15];
// C/D: col=lane&15, row=quad*4+reg (m89-verified).
__global__ __launch_bounds__(256, 2) void p1_gemm(
    const float* __restrict__ W1,
    const float* __restrict__ b1,
    const __bf16* __restrict__ W2T,
    const float* __restrict__ b2,
    const float* __restrict__ W3,
    const float* __restrict__ b3,
    float* __restrict__ V)
{
  __shared__ __align__(16) __bf16 Alds[64 * 40];    // 64 rows x 32 k, pad->40
  __shared__ __align__(16) __bf16 Blds[512 * 40];   // 512 cols x 32 k, pad->40
  __shared__ float red[4][64];

  const int tid  = threadIdx.x;
  const int bm   = blockIdx.x * 64;
  const int wave = tid >> 6;
  const int lane = tid & 63;
  const int quad = lane >> 4;
  const int l15  = lane & 15;

  // A-staging: 4 threads per row, each computes 8 h1 values per K-iter
  const int arow = tid >> 2;
  const int jb   = (tid & 3) * 8;
  const int r    = bm + arow;
  const int n    = r / G_PTS;
  const int g    = r - n * G_PTS;
  const float t  = (float)n * DT_F;
  const float yg = Y_LO + (float)(g - 1) * DY;   // halo point at g=0

  floatx4 acc[4][8];
  #pragma unroll
  for (int mt = 0; mt < 4; ++mt)
    #pragma unroll
    for (int nt = 0; nt < 8; ++nt){
      floatx4 z = {0.f, 0.f, 0.f, 0.f};
      acc[mt][nt] = z;
    }

  for (int kk = 0; kk < HID; kk += 32){
    // stage A: h1_j = tanh(t*W1[0,j] + y*W1[1,j] + b1[j]) for j = kk+jb..+7
    {
      const float* wt = W1 + kk + jb;          // row 0 of W1 (t weight)
      const float* wy = W1 + 512 + kk + jb;    // row 1 of W1 (y weight)
      const float* bp = b1 + kk + jb;
      bf16x8 hv;
      #pragma unroll
      for (int e = 0; e < 8; ++e){
        float z = fmaf(t, wt[e], fmaf(yg, wy[e], bp[e]));
        hv[e] = (__bf16)tanh_fast(z);
      }
      *reinterpret_cast<bf16x8*>(&Alds[arow * 40 + jb]) = hv;
    }
    // stage B: Blds[col][k] = W2T[col][kk+k]
    #pragma unroll
    for (int c8 = 0; c8 < 8; ++c8){
      int c = tid + c8 * 256;                  // 0..2047
      int nn = c >> 2, part = c & 3;
      bf16x8 v = *reinterpret_cast<const bf16x8*>(&W2T[nn * 512 + kk + part * 8]);
      *reinterpret_cast<bf16x8*>(&Blds[nn * 40 + part * 8]) = v;
    }
    __syncthreads();

    bf16x8 aF[4];
    #pragma unroll
    for (int mt = 0; mt < 4; ++mt)
      aF[mt] = *reinterpret_cast<const bf16x8*>(&Alds[(mt * 16 + l15) * 40 + quad * 8]);
    #pragma unroll
    for (int nt = 0; nt < 8; ++nt){
      bf16x8 bF = *reinterpret_cast<const bf16x8*>(&Blds[(wave * 128 + nt * 16 + l15) * 40 + quad * 8]);
      #pragma unroll
      for (int mt = 0; mt < 4; ++mt)
        acc[mt][nt] = __builtin_amdgcn_mfma_f32_16x16x32_bf16(aF[mt], bF, acc[mt][nt], 0, 0, 0);
    }
    __syncthreads();
  }

  // epilogue: V[row] = b3 + sum_k W3[k] * tanh(z[row][k] + b2[k])
  float p[4][4];
  #pragma unroll
  for (int mt = 0; mt < 4; ++mt)
    #pragma unroll
    for (int rg = 0; rg < 4; ++rg) p[mt][rg] = 0.f;

  #pragma unroll
  for (int nt = 0; nt < 8; ++nt){
    int col = wave * 128 + nt * 16 + l15;
    float b2v = b2[col];
    float w3v = W3[col];
    #pragma unroll
    for (int mt = 0; mt < 4; ++mt)
      #pragma unroll
      for (int rg = 0; rg < 4; ++rg)
        p[mt][rg] += tanh_fast(acc[mt][nt][rg] + b2v) * w3v;
  }
  #pragma unroll
  for (int off = 1; off < 16; off <<= 1)
    #pragma unroll
    for (int mt = 0; mt < 4; ++mt)
      #pragma unroll
      for (int rg = 0; rg < 4; ++rg)
        p[mt][rg] += __shfl_xor(p[mt][rg], off, 64);

  if (l15 == 0){
    #pragma unroll
    for (int mt = 0; mt < 4; ++mt)
      #pragma unroll
      for (int rg = 0; rg < 4; ++rg)
        red[wave][mt * 16 + quad * 4 + rg] = p[mt][rg];
  }
  __syncthreads();
  if (tid < 64){
    float s = red[0][tid] + red[1][tid] + red[2][tid] + red[3][tid] + b3[0];
    V[bm + tid] = s;
  }
}

// ---------------- P1c: Catmull-Rom coeffs per (step, cell) ---------------------
__global__ __launch_bounds__(256) void p1_coeff(const float* __restrict__ V,
                                                float4* __restrict__ C,
                                                float* __restrict__ sum_out){
  if (blockIdx.x == 0 && threadIdx.x == 0) sum_out[0] = 0.f;
  int cell = blockIdx.x * 256 + threadIdx.x;   // 64000 total
  int nn = cell >> 6;
  int j  = cell & 63;
  const float* v = &V[nn * G_PTS + j];
  float pm1 = v[0], p0 = v[1], p1 = v[2], p2 = v[3];
  float4 c;
  c.x = p0;
  c.y = 0.5f * (p1 - pm1);
  c.z = pm1 - 2.5f * p0 + 2.0f * p1 - 0.5f * p2;
  c.w = 1.5f * (p0 - p1) + 0.5f * (p2 - pm1);
  C[cell] = c;
}

// ---------------- P2: the serial scan, one thread per batch element ------------
// 1 wave/block. Double-buffered 16-step LDS chunks via global_load_lds DMA.
// Per 8-step block: dW LDS reads -> Brownian-prefix index prediction -> 8
// predicted ds_read_b128 gathers -> exact chain at VALU latency.
__global__ __launch_bounds__(64) void p2_scan(
    const float* __restrict__ eps,
    const float* __restrict__ dW,
    const float* __restrict__ qm,
    const float* __restrict__ qlv,
    const float4* __restrict__ Cin,
    float* __restrict__ out,
    float* __restrict__ sum_out)
{
  __shared__ __align__(16) floatx4 cl[2][16][64];   // 32 KB: C rows, 16 steps x 2 bufs
  __shared__ float dwl[2][16][64];                  //  8 KB: dW,    16 steps x 2 bufs

  const int lane = threadIdx.x;          // 0..63 (one wave)
  const int i    = blockIdx.x * 64 + lane;
  const floatx4* C = reinterpret_cast<const floatx4*>(Cin);

  float qmean = qm[0];
  float qstd  = __expf(0.5f * qlv[0]);
  float yv0 = fmaf(gload(eps + i), qstd, qmean);
  float vst = fmaf(yv0, 8.0f, 32.0f);    // u-space state (v = 8y+32)
  float acc2 = 0.f;
  float* orow = out + (size_t)i * NUM_STEPS;

  floatx4 ybuf = {0.f, 0.f, 0.f, 0.f};

#define ISSUE_CHUNK(CH)                                                        \
  { const int bse_ = (CH) * 16; const int bf_ = (CH) & 1;                      \
    _Pragma("unroll")                                                          \
    for (int k2 = 0; k2 < 16; ++k2){                                           \
      int rr = bse_ + k2; rr = rr > 999 ? 999 : rr;                            \
      dma16(&C[rr * G_CELLS + lane], (void*)&cl[bf_][k2][0]);                  \
      dma4 (&dW[rr * BATCH + i],     (void*)&dwl[bf_][k2][0]);                 \
    } }

#define GBLOCK(ST0)                                                            \
  { const int bf_ = ((ST0) >> 4) & 1; const int sl_ = (ST0) & 15;              \
    float fdw[8], jf[8]; floatx4 gv[8];                                        \
    _Pragma("unroll")                                                          \
    for (int k = 0; k < 8; ++k) fdw[k] = 4.0f * dwl[bf_][sl_ + k][lane];       \
    /* index prediction: v_hat_k = v_B + 4*sum_{m<k} dw_m (k=0 exact) */       \
    float pv = vst;                                                            \
    _Pragma("unroll")                                                          \
    for (int k = 0; k < 8; ++k){                                               \
      float up = __builtin_amdgcn_fmed3f(pv, 0.0f, 63.999f);                   \
      int jp = (int)up; jf[k] = (float)jp;                                     \
      gv[k] = cl[bf_][sl_ + k][jp];        /* predicted ds_read_b128 */        \
      pv += fdw[k];                                                            \
    }                                                                          \
    /* exact chain at VALU speed (C^1 spline: s slightly outside [0,1) ok) */  \
    _Pragma("unroll")                                                          \
    for (int k = 0; k < 8; ++k){                                               \
      float u  = __builtin_amdgcn_fmed3f(vst, 0.0f, 63.999f);                  \
      float t1 = vst + fdw[k];                                                 \
      float q  = fmaf(vst, 0.25f, -10.0f);   /* 2y-2 in u-space */             \
      float s  = u - jf[k];                                                    \
      float tlo = fmaf(s, gv[k][1], gv[k][0]);                                 \
      float thi = fmaf(s, gv[k][3], gv[k][2]);                                 \
      float s2 = s * s;                                                        \
      float f  = fmaf(s2, thi, tlo);                                           \
      float uu = fmaf(2.0f, f, q);                                             \
      acc2 = fmaf(uu, uu, acc2);                                               \
      vst = fmaf(f, 8.0f * DT_F, t1);        /* exact 8x of y-space step */    \
      float yo = fmaf(vst, 0.125f, -4.0f);                                     \
      if      ((k & 3) == 0) ybuf[0] = yo;                                     \
      else if ((k & 3) == 1) ybuf[1] = yo;                                     \
      else if ((k & 3) == 2) ybuf[2] = yo;                                     \
      else { ybuf[3] = yo;                                                     \
             gstore(reinterpret_cast<floatx4*>(orow + (ST0) + k - 3), ybuf); } \
    } }

  // prologue: issue chunks 0 and 1 (64 DMA ops), wait for chunk 0 (32 remain)
  ISSUE_CHUNK(0);
  ISSUE_CHUNK(1);
  asm volatile("s_waitcnt vmcnt(32)" ::: "memory");
  __builtin_amdgcn_sched_barrier(0);

  // chunks 0..61 = steps 0..991; per iter: consume chunk c, wait chunk c+1
  // (issued one full chunk ago; 4 trailing stores -> vmcnt(4)), issue c+2.
  for (int c = 0; c < 62; ++c){
    const int st0 = c << 4;
    GBLOCK(st0);
    GBLOCK(st0 + 8);
    asm volatile("s_waitcnt vmcnt(4)" ::: "memory");
    __builtin_amdgcn_sched_barrier(0);
    if (c < 61){ ISSUE_CHUNK(c + 2); }   // c=60 issues tail chunk 62
    __builtin_amdgcn_sched_barrier(0);
  }
  // tail: steps 992..999 from chunk 62 (buf 0), waited at c=61
  GBLOCK(992);
#undef GBLOCK
#undef ISSUE_CHUNK

  float lq = 0.5f * DT_F * acc2;
  #pragma unroll
  for (int off = 1; off < 64; off <<= 1)
    lq += __shfl_xor(lq, off, 64);
  if (lane == 0) atomicAdd(sum_out, lq);
}

// ---------------- P3: kl0 + mean(logqp) -> out[last] ---------------------------
__global__ void p3_final(const float* __restrict__ qm,
                         const float* __restrict__ qlv,
                         const float* __restrict__ sum_in,
                         float* __restrict__ out){
  float qmean = qm[0];
  float qstd  = __expf(0.5f * qlv[0]);
  const float pstd = 0.35355339059327373f;        // sigma/sqrt(2*theta)
  float ratio = qstd / pstd;
  float dm = 1.0f - qmean;                        // MU - qy0_mean
  float kl0 = 0.5f * (ratio * ratio + (dm * dm) / (pstd * pstd)
                      - 1.0f + __logf(pstd / qstd));
  out[(size_t)BATCH * NUM_STEPS] = kl0 + sum_in[0] * (1.0f / 32768.0f);
}

extern "C" void kernel_launch(void* const* d_in, const int* in_sizes, int n_in,
                              void* d_out, int out_size, void* d_ws, size_t ws_size,
                              hipStream_t stream){
  const float* W1  = (const float*)d_in[0];
  const float* b1  = (const float*)d_in[1];
  const float* W2  = (const float*)d_in[2];
  const float* b2  = (const float*)d_in[3];
  const float* W3  = (const float*)d_in[4];
  const float* b3  = (const float*)d_in[5];
  const float* qm  = (const float*)d_in[6];
  const float* qlv = (const float*)d_in[7];
  const float* eps = (const float*)d_in[8];
  const float* dW  = (const float*)d_in[9];
  float* out = (float*)d_out;

  // workspace: W2T 512KB | V 272KB | C 1MB | sum
  char* ws = (char*)d_ws;
  __bf16* W2T = (__bf16*)(ws);
  float*  V   = (float*)(ws + 524288);
  float4* C   = (float4*)(ws + 796416);
  float*  sum = (float*)(ws + 1820416);

  p0_transpose<<<256, 256, 0, stream>>>(W2, W2T);
  p1_gemm<<<P1_BLOCKS, 256, 0, stream>>>(W1, b1, W2T, b2, W3, b3, V);
  p1_coeff<<<250, 256, 0, stream>>>(V, C, sum);
  p2_scan<<<BATCH / 64, 64, 0, stream>>>(eps, dW, qm, qlv, C, out, sum);
  p3_final<<<1, 1, 0, stream>>>(qm, qlv, sum, out);
}

// Round 7
// 355.702 us; speedup vs baseline: 1.2347x; 1.2014x over previous
//
#include <hip/hip_runtime.h>
#include <hip/hip_bf16.h>

// LatentSDE: y' = f_post(t,y) dt + sigma dW, f_post = MLP(2->512->512->1, tanh).
// Phase 1: tabulate f per (t-slab, y-grid) via fused MFMA GEMM. Round-7: t-grid
//   SUBSAMPLED 8x (126 slabs x 68 y-points = 8568 rows; f is smooth in t —
//   linear-in-t interp error ~1e-5 vs 0.0156 y-interp budget). 7.9x fewer FLOPs.
// Phase 1c: lerp slabs -> per-step Catmull-Rom coeffs (C layout unchanged).
// Phase 2: serial scan. Round-7: PRODUCER-CONSUMER WAVE SPECIALIZATION.
//   r6 measured ~5000cy completion for a 32-op global_load_lds chunk (per-wave
//   LDS-DMA queue serialization) — per-wave prefetch cannot hide it. Now wave 1
//   (producer) does global->reg->ds_write into a TRIPLE-buffered LDS chunk
//   store; its ~900cy HBM stall runs parallel to wave 0 (consumer), whose chunk
//   time is pure chain compute. Raw s_barrier only (no counter drain); loads
//   are short-lived (no register-ring allocator fight — r4/r5 lesson).
//   Consumer per 8-step block (r4/r6 structure, accuracy-validated): Brownian-
//   prefix index prediction -> 8 ds_read_b128 gathers -> exact chain at VALU
//   dependency speed.

typedef __bf16 bf16x8 __attribute__((ext_vector_type(8)));
typedef float floatx4 __attribute__((ext_vector_type(4)));

#define NUM_STEPS 1000
#define BATCH 32768
#define HID 512
#define G_PTS 68             // stored y-grid points per slab (64 cells + CR halo)
#define G_CELLS 64
#define T_SUB 8              // t-subsample factor
#define N_SLAB 126           // slabs at t = m*0.008, m=0..125 (covers n<=999)
#define P1_ROWS (N_SLAB * G_PTS)   // 8568
#define P1_BLOCKS 134        // * 64 rows = 8576 >= 8568
#define DT_F 0.001f
#define DT_SLAB 0.008f
#define Y_LO (-4.0f)
#define DY 0.125f
#define INV_DY 8.0f

// force global (addrspace 1) memory ops — guarantees global_*, never flat_*
// (values must be ext_vector_type, not HIP float4 — r2 compile lesson)
template <typename T>
__device__ __forceinline__ T gload(const T* p){
  return *(const T __attribute__((address_space(1)))*)((unsigned long long)p);
}
template <typename T>
__device__ __forceinline__ void gstore(T* p, T v){
  *(T __attribute__((address_space(1)))*)((unsigned long long)p) = v;
}

// tanh(x) = 1 - 2/(exp(2x)+1); saturates correctly for |x| large
__device__ __forceinline__ float tanh_fast(float x){
  float e = __expf(2.0f * x);
  return 1.0f - 2.0f / (e + 1.0f);
}

// ---------------- P0: W2 f32 [k][j] -> W2T bf16 [j][k] (512x512) ---------------
__global__ __launch_bounds__(256) void p0_transpose(const float* __restrict__ W2,
                                                    __bf16* __restrict__ W2T){
  int tid = blockIdx.x * 256 + threadIdx.x;
  #pragma unroll
  for (int r = 0; r < 4; ++r){
    int idx = tid + r * 65536;
    int a = idx >> 9, b = idx & 511;
    W2T[a * 512 + b] = (__bf16)W2[b * 512 + a];   // W2T[j][k] = W2[k][j]
  }
}

// ---------------- P1: h1 -> GEMM(W2) -> tanh -> dot(W3) => V[m*68+g] -----------
// Rows are (t-slab m, y-grid g); t = m * DT_SLAB. Structure unchanged from the
// verified kernel; only the row->(t,y) mapping and block count changed.
__global__ __launch_bounds__(256, 2) void p1_gemm(
    const float* __restrict__ W1,
    const float* __restrict__ b1,
    const __bf16* __restrict__ W2T,
    const float* __restrict__ b2,
    const float* __restrict__ W3,
    const float* __restrict__ b3,
    float* __restrict__ V)
{
  __shared__ __align__(16) __bf16 Alds[64 * 40];    // 64 rows x 32 k, pad->40
  __shared__ __align__(16) __bf16 Blds[512 * 40];   // 512 cols x 32 k, pad->40
  __shared__ float red[4][64];

  const int tid  = threadIdx.x;
  const int bm   = blockIdx.x * 64;
  const int wave = tid >> 6;
  const int lane = tid & 63;
  const int quad = lane >> 4;
  const int l15  = lane & 15;

  // A-staging: 4 threads per row, each computes 8 h1 values per K-iter
  const int arow = tid >> 2;
  const int jb   = (tid & 3) * 8;
  const int r    = bm + arow;
  const int n    = r / G_PTS;                    // slab index
  const int g    = r - n * G_PTS;
  const float t  = (float)n * DT_SLAB;
  const float yg = Y_LO + (float)(g - 1) * DY;   // halo point at g=0

  floatx4 acc[4][8];
  #pragma unroll
  for (int mt = 0; mt < 4; ++mt)
    #pragma unroll
    for (int nt = 0; nt < 8; ++nt){
      floatx4 z = {0.f, 0.f, 0.f, 0.f};
      acc[mt][nt] = z;
    }

  for (int kk = 0; kk < HID; kk += 32){
    // stage A: h1_j = tanh(t*W1[0,j] + y*W1[1,j] + b1[j]) for j = kk+jb..+7
    {
      const float* wt = W1 + kk + jb;          // row 0 of W1 (t weight)
      const float* wy = W1 + 512 + kk + jb;    // row 1 of W1 (y weight)
      const float* bp = b1 + kk + jb;
      bf16x8 hv;
      #pragma unroll
      for (int e = 0; e < 8; ++e){
        float z = fmaf(t, wt[e], fmaf(yg, wy[e], bp[e]));
        hv[e] = (__bf16)tanh_fast(z);
      }
      *reinterpret_cast<bf16x8*>(&Alds[arow * 40 + jb]) = hv;
    }
    // stage B: Blds[col][k] = W2T[col][kk+k]
    #pragma unroll
    for (int c8 = 0; c8 < 8; ++c8){
      int c = tid + c8 * 256;                  // 0..2047
      int nn = c >> 2, part = c & 3;
      bf16x8 v = *reinterpret_cast<const bf16x8*>(&W2T[nn * 512 + kk + part * 8]);
      *reinterpret_cast<bf16x8*>(&Blds[nn * 40 + part * 8]) = v;
    }
    __syncthreads();

    bf16x8 aF[4];
    #pragma unroll
    for (int mt = 0; mt < 4; ++mt)
      aF[mt] = *reinterpret_cast<const bf16x8*>(&Alds[(mt * 16 + l15) * 40 + quad * 8]);
    #pragma unroll
    for (int nt = 0; nt < 8; ++nt){
      bf16x8 bF = *reinterpret_cast<const bf16x8*>(&Blds[(wave * 128 + nt * 16 + l15) * 40 + quad * 8]);
      #pragma unroll
      for (int mt = 0; mt < 4; ++mt)
        acc[mt][nt] = __builtin_amdgcn_mfma_f32_16x16x32_bf16(aF[mt], bF, acc[mt][nt], 0, 0, 0);
    }
    __syncthreads();
  }

  // epilogue: V[row] = b3 + sum_k W3[k] * tanh(z[row][k] + b2[k])
  float p[4][4];
  #pragma unroll
  for (int mt = 0; mt < 4; ++mt)
    #pragma unroll
    for (int rg = 0; rg < 4; ++rg) p[mt][rg] = 0.f;

  #pragma unroll
  for (int nt = 0; nt < 8; ++nt){
    int col = wave * 128 + nt * 16 + l15;
    float b2v = b2[col];
    float w3v = W3[col];
    #pragma unroll
    for (int mt = 0; mt < 4; ++mt)
      #pragma unroll
      for (int rg = 0; rg < 4; ++rg)
        p[mt][rg] += tanh_fast(acc[mt][nt][rg] + b2v) * w3v;
  }
  #pragma unroll
  for (int off = 1; off < 16; off <<= 1)
    #pragma unroll
    for (int mt = 0; mt < 4; ++mt)
      #pragma unroll
      for (int rg = 0; rg < 4; ++rg)
        p[mt][rg] += __shfl_xor(p[mt][rg], off, 64);

  if (l15 == 0){
    #pragma unroll
    for (int mt = 0; mt < 4; ++mt)
      #pragma unroll
      for (int rg = 0; rg < 4; ++rg)
        red[wave][mt * 16 + quad * 4 + rg] = p[mt][rg];
  }
  __syncthreads();
  if (tid < 64){
    float s = red[0][tid] + red[1][tid] + red[2][tid] + red[3][tid] + b3[0];
    V[bm + tid] = s;
  }
}

// ---------------- P1c: t-lerp slabs + Catmull-Rom coeffs per (step, cell) ------
__global__ __launch_bounds__(256) void p1_coeff(const float* __restrict__ V,
                                                float4* __restrict__ C,
                                                float* __restrict__ sum_out){
  if (blockIdx.x == 0 && threadIdx.x == 0) sum_out[0] = 0.f;
  int cell = blockIdx.x * 256 + threadIdx.x;   // 64000 total
  int nn = cell >> 6;                          // step 0..999
  int j  = cell & 63;
  int m  = nn >> 3;                            // slab
  float a = (float)(nn & 7) * 0.125f;          // t-lerp weight
  const float* va = &V[m * G_PTS + j];         // V_sub is 34KB -> L2-resident
  const float* vb = &V[(m + 1) * G_PTS + j];
  float pm1 = fmaf(a, vb[0] - va[0], va[0]);
  float p0  = fmaf(a, vb[1] - va[1], va[1]);
  float p1  = fmaf(a, vb[2] - va[2], va[2]);
  float p2  = fmaf(a, vb[3] - va[3], va[3]);
  float4 c;
  c.x = p0;
  c.y = 0.5f * (p1 - pm1);
  c.z = pm1 - 2.5f * p0 + 2.0f * p1 - 0.5f * p2;
  c.w = 1.5f * (p0 - p1) + 0.5f * (p2 - pm1);
  C[cell] = c;
}

// ---------------- P2: scan with producer/consumer wave specialization ----------
// Block = 128 thr: wave 0 = consumer (64 chains), wave 1 = producer.
// Triple-buffered 16-step LDS chunks; producer global->reg->ds_write; raw
// s_barrier only (counters never drained across waves' in-flight ops).
__global__ __launch_bounds__(128) void p2_scan(
    const float* __restrict__ eps,
    const float* __restrict__ dW,
    const float* __restrict__ qm,
    const float* __restrict__ qlv,
    const float4* __restrict__ Cin,
    float* __restrict__ out,
    float* __restrict__ sum_out)
{
  __shared__ __align__(16) floatx4 cl[3][16][64];   // 48 KB: C rows
  __shared__ float dwl[3][16][64];                  // 12 KB: dW
  const int tid  = threadIdx.x;
  const int wv   = tid >> 6;
  const int lane = tid & 63;
  const int i0   = blockIdx.x * 64;
  const floatx4* C = reinterpret_cast<const floatx4*>(Cin);

  if (wv == 1){
    // ---------------- producer wave ----------------
#define PROD_STAGE(CH, BUF)                                                    \
    { const int n0_ = (CH) << 4;                                               \
      floatx4 tc_[16]; floatx4 td_[4];                                         \
      _Pragma("unroll")                                                        \
      for (int q = 0; q < 16; ++q){                                            \
        int rr = n0_ + q; rr = rr > 999 ? 999 : rr;                            \
        tc_[q] = gload(C + rr * G_CELLS + lane);                               \
      }                                                                        \
      _Pragma("unroll")                                                        \
      for (int p = 0; p < 4; ++p){                                             \
        int rr = n0_ + p * 4 + (lane >> 4); rr = rr > 999 ? 999 : rr;          \
        td_[p] = gload(reinterpret_cast<const floatx4*>(                       \
                   dW + (size_t)rr * BATCH + i0 + ((lane & 15) << 2)));        \
      }                                                                        \
      asm volatile("s_waitcnt vmcnt(0)" ::: "memory");                         \
      _Pragma("unroll")                                                        \
      for (int q = 0; q < 16; ++q) cl[BUF][q][lane] = tc_[q];                  \
      _Pragma("unroll")                                                        \
      for (int p = 0; p < 4; ++p)                                              \
        *reinterpret_cast<floatx4*>(&dwl[BUF][p * 4 + (lane >> 4)][(lane & 15) << 2]) = td_[p]; \
      asm volatile("s_waitcnt lgkmcnt(0)" ::: "memory");                       \
    }
    PROD_STAGE(0, 0)
    PROD_STAGE(1, 1)
    __builtin_amdgcn_s_barrier();
    __builtin_amdgcn_sched_barrier(0);
    // iter c: write chunk c+2 into buf (c+2)%3 while consumer reads buf c%3
    for (int c3 = 0; c3 < 63; c3 += 3){
      { PROD_STAGE(c3 + 2, 2) }
      __builtin_amdgcn_s_barrier(); __builtin_amdgcn_sched_barrier(0);
      if (c3 + 3 <= 62) PROD_STAGE(c3 + 3, 0)
      __builtin_amdgcn_s_barrier(); __builtin_amdgcn_sched_barrier(0);
      if (c3 + 4 <= 62) PROD_STAGE(c3 + 4, 1)
      __builtin_amdgcn_s_barrier(); __builtin_amdgcn_sched_barrier(0);
    }
#undef PROD_STAGE
  } else {
    // ---------------- consumer wave ----------------
    float qmean = qm[0];
    float qstd  = __expf(0.5f * qlv[0]);
    float yv0 = fmaf(gload(eps + i0 + lane), qstd, qmean);
    float vst = fmaf(yv0, 8.0f, 32.0f);      // u-space state (v = 8y+32)
    float acc2 = 0.f;
    float* orow = out + (size_t)(i0 + lane) * NUM_STEPS;
    floatx4 ybuf = {0.f, 0.f, 0.f, 0.f};
    __builtin_amdgcn_s_barrier();
    __builtin_amdgcn_sched_barrier(0);

#define GBLOCK(ST0, BUF, SL)                                                   \
    { float fdw[8], jf[8]; floatx4 gv[8];                                      \
      _Pragma("unroll")                                                        \
      for (int k = 0; k < 8; ++k) fdw[k] = 4.0f * dwl[BUF][(SL) + k][lane];    \
      /* index prediction: v_hat_k = v_blk + 4*sum_{m<k} dw_m (k=0 exact) */   \
      float pv = vst;                                                          \
      _Pragma("unroll")                                                        \
      for (int k = 0; k < 8; ++k){                                             \
        float up = __builtin_amdgcn_fmed3f(pv, 0.0f, 63.999f);                 \
        int jp = (int)up; jf[k] = (float)jp;                                   \
        gv[k] = cl[BUF][(SL) + k][jp];       /* predicted ds_read_b128 */      \
        pv += fdw[k];                                                          \
      }                                                                        \
      /* exact chain at VALU speed (C^1 spline: s slightly outside [0,1) ok) */\
      _Pragma("unroll")                                                        \
      for (int k = 0; k < 8; ++k){                                             \
        float u  = __builtin_amdgcn_fmed3f(vst, 0.0f, 63.999f);                \
        float t1 = vst + fdw[k];                                               \
        float q  = fmaf(vst, 0.25f, -10.0f);   /* 2y-2 in u-space */           \
        float s  = u - jf[k];                                                  \
        float tlo = fmaf(s, gv[k][1], gv[k][0]);                               \
        float thi = fmaf(s, gv[k][3], gv[k][2]);                               \
        float s2 = s * s;                                                      \
        float f  = fmaf(s2, thi, tlo);                                         \
        float uu = fmaf(2.0f, f, q);                                           \
        acc2 = fmaf(uu, uu, acc2);                                             \
        vst = fmaf(f, 8.0f * DT_F, t1);        /* exact 8x of y-space step */  \
        float yo = fmaf(vst, 0.125f, -4.0f);                                   \
        if      ((k & 3) == 0) ybuf[0] = yo;                                   \
        else if ((k & 3) == 1) ybuf[1] = yo;                                   \
        else if ((k & 3) == 2) ybuf[2] = yo;                                   \
        else { ybuf[3] = yo;                                                   \
               gstore(reinterpret_cast<floatx4*>(orow + (ST0) + k - 3), ybuf); } \
      } }
#define CONS_ITER(CC, BUF)                                                     \
    { const int st0_ = (CC) << 4;                                              \
      GBLOCK(st0_, BUF, 0)                                                     \
      if ((CC) < 62) GBLOCK(st0_ + 8, BUF, 8)                                  \
      __builtin_amdgcn_s_barrier();                                            \
      __builtin_amdgcn_sched_barrier(0); }

    for (int c3 = 0; c3 < 63; c3 += 3){
      CONS_ITER(c3, 0)
      CONS_ITER(c3 + 1, 1)
      CONS_ITER(c3 + 2, 2)
    }
#undef CONS_ITER
#undef GBLOCK

    float lq = 0.5f * DT_F * acc2;
    #pragma unroll
    for (int off = 1; off < 64; off <<= 1)
      lq += __shfl_xor(lq, off, 64);
    if (lane == 0) atomicAdd(sum_out, lq);
  }
}

// ---------------- P3: kl0 + mean(logqp) -> out[last] ---------------------------
__global__ void p3_final(const float* __restrict__ qm,
                         const float* __restrict__ qlv,
                         const float* __restrict__ sum_in,
                         float* __restrict__ out){
  float qmean = qm[0];
  float qstd  = __expf(0.5f * qlv[0]);
  const float pstd = 0.35355339059327373f;        // sigma/sqrt(2*theta)
  float ratio = qstd / pstd;
  float dm = 1.0f - qmean;                        // MU - qy0_mean
  float kl0 = 0.5f * (ratio * ratio + (dm * dm) / (pstd * pstd)
                      - 1.0f + __logf(pstd / qstd));
  out[(size_t)BATCH * NUM_STEPS] = kl0 + sum_in[0] * (1.0f / 32768.0f);
}

extern "C" void kernel_launch(void* const* d_in, const int* in_sizes, int n_in,
                              void* d_out, int out_size, void* d_ws, size_t ws_size,
                              hipStream_t stream){
  const float* W1  = (const float*)d_in[0];
  const float* b1  = (const float*)d_in[1];
  const float* W2  = (const float*)d_in[2];
  const float* b2  = (const float*)d_in[3];
  const float* W3  = (const float*)d_in[4];
  const float* b3  = (const float*)d_in[5];
  const float* qm  = (const float*)d_in[6];
  const float* qlv = (const float*)d_in[7];
  const float* eps = (const float*)d_in[8];
  const float* dW  = (const float*)d_in[9];
  float* out = (float*)d_out;

  // workspace: W2T 512KB | V 272KB | C 1MB | sum
  char* ws = (char*)d_ws;
  __bf16* W2T = (__bf16*)(ws);
  float*  V   = (float*)(ws + 524288);
  float4* C   = (float4*)(ws + 796416);
  float*  sum = (float*)(ws + 1820416);

  p0_transpose<<<256, 256, 0, stream>>>(W2, W2T);
  p1_gemm<<<P1_BLOCKS, 256, 0, stream>>>(W1, b1, W2T, b2, W3, b3, V);
  p1_coeff<<<250, 256, 0, stream>>>(V, C, sum);
  p2_scan<<<BATCH / 64, 128, 0, stream>>>(eps, dW, qm, qlv, C, out, sum);
  p3_final<<<1, 1, 0, stream>>>(qm, qlv, sum, out);
}